// Round 2
// baseline (1237.722 us; speedup 1.0000x reference)
//
#include <hip/hip_runtime.h>
#include <stdint.h>

typedef unsigned short u16;
typedef unsigned char u8;
typedef short bf16x8 __attribute__((ext_vector_type(8)));
typedef float f32x4 __attribute__((ext_vector_type(4)));
typedef u16 u16x4 __attribute__((ext_vector_type(4)));

#define Bn 2048
#define Sn 64
#define Dn 512
#define Hn 8
#define MTOT (Bn*Sn)

__device__ __forceinline__ u16 f2bf(float f){
  uint32_t u = __builtin_bit_cast(uint32_t, f);
  u += 0x7FFFu + ((u>>16)&1u);   // round-to-nearest-even
  return (u16)(u>>16);
}

__device__ __forceinline__ void gload16(const void* g, void* lds){
  __builtin_amdgcn_global_load_lds((const __attribute__((address_space(1))) void*)g,
                                   (__attribute__((address_space(3))) void*)lds, 16, 0, 0);
}

// ---------------- weight conversion fp32 -> bf16 ----------------
__global__ __launch_bounds__(256) void wconv_k(
    const float* __restrict__ Wq, const float* __restrict__ Wk,
    const float* __restrict__ Wv, const float* __restrict__ Wo,
    u16* __restrict__ Wqkv, u16* __restrict__ Wob)
{
  int t = blockIdx.x*256 + threadIdx.x;      // 0..262143, 4 floats each
  int mat = t>>16, i4 = t&65535;
  const float4* src = (mat==0)?(const float4*)Wq:(mat==1)?(const float4*)Wk:
                      (mat==2)?(const float4*)Wv:(const float4*)Wo;
  float4 v = src[i4];
  u16x4 o; o.x=f2bf(v.x); o.y=f2bf(v.y); o.z=f2bf(v.z); o.w=f2bf(v.w);
  if (mat<3) ((u16x4*)Wqkv)[t] = o;
  else       ((u16x4*)Wob)[i4] = o;
}

// ---------------- K1: QKV projection GEMM ----------------
// A = x (fp32, reg-staged + cvt to bf16, swizzled LDS write)
// B = Wqkv bf16 (B^T layout), global_load_lds w/ pre-swizzled source
// C: Q,K as [b][h][s][hd]; V transposed -> Vt [b][h][hd][s]
__global__ __launch_bounds__(256) void k1_qkv(
    const float* __restrict__ X, const u16* __restrict__ W,
    const float* __restrict__ bq, const float* __restrict__ bk, const float* __restrict__ bv,
    u16* __restrict__ Q, u16* __restrict__ Kb, u16* __restrict__ Vt)
{
  __shared__ __align__(16) u16 As[8192];   // [128 rows][64 k] bf16, byte ^= (row&7)<<4
  __shared__ __align__(16) u16 Bs[8192];
  const int tid = threadIdx.x, lane = tid&63, wv = tid>>6;
  const int jbase = blockIdx.x<<7;     // 0..1535 (grid.x = 12)
  const int rbase = blockIdx.y<<7;
  const int wr = (wv>>1)<<6, wc = (wv&1)<<6;
  f32x4 acc[4][4] = {};

  for (int kt=0; kt<8; ++kt){
    const float* xs = X + (size_t)rbase*Dn + kt*64;
    #pragma unroll
    for (int j=0;j<8;++j){             // A: 8192 floats, 8 float4/thread
      int f = j*256 + tid;
      int arow = f>>4;
      int kb = (f&15)<<3;              // byte offset within 128B row
      float4 xv = *(const float4*)(xs + (size_t)arow*Dn + (kb>>1));
      u16x4 hv; hv.x=f2bf(xv.x); hv.y=f2bf(xv.y); hv.z=f2bf(xv.z); hv.w=f2bf(xv.w);
      int off = (arow<<7) + (kb ^ ((arow&7)<<4));
      *(u16x4*)((char*)As + off) = hv;
    }
    #pragma unroll
    for (int i=0;i<4;++i){             // B: 16KB via 16 wave-issues of 1KB
      int chunk = (wv<<2) + i;
      int brow = (chunk<<3) + (lane>>3);
      int inner = (lane&7)<<4;
      int srcb = ((jbase + brow)<<10) + (kt<<7) + (inner ^ ((brow&7)<<4));
      gload16((const char*)W + srcb, (char*)Bs + (chunk<<10));
    }
    __syncthreads();
    bf16x8 af[4][2], bfr[4][2];
    #pragma unroll
    for (int m=0;m<4;++m){
      int row = wr + (m<<4) + (lane&15);
      #pragma unroll
      for (int kk=0;kk<2;++kk){
        int koff = ((((kk<<2)+(lane>>4)) ^ (row&7))<<4);
        af[m][kk] = *(const bf16x8*)((char*)As + (row<<7) + koff);
      }
    }
    #pragma unroll
    for (int n=0;n<4;++n){
      int row = wc + (n<<4) + (lane&15);
      #pragma unroll
      for (int kk=0;kk<2;++kk){
        int koff = ((((kk<<2)+(lane>>4)) ^ (row&7))<<4);
        bfr[n][kk] = *(const bf16x8*)((char*)Bs + (row<<7) + koff);
      }
    }
    #pragma unroll
    for (int m=0;m<4;++m)
      #pragma unroll
      for (int n=0;n<4;++n){
        acc[m][n] = __builtin_amdgcn_mfma_f32_16x16x32_bf16(af[m][0], bfr[n][0], acc[m][n], 0,0,0);
        acc[m][n] = __builtin_amdgcn_mfma_f32_16x16x32_bf16(af[m][1], bfr[n][1], acc[m][n], 0,0,0);
      }
    __syncthreads();
  }
  // epilogue: bias + bf16 + scatter to head-blocked layouts
  const int mat = jbase>>9;            // 0=Q 1=K 2=V
  const float* bias = (mat==0)?bq:((mat==1)?bk:bv);
  u16* Out = (mat==0)?Q:((mat==1)?Kb:Vt);
  const int jb = jbase & 511;
  #pragma unroll
  for (int n=0;n<4;++n){
    int jl = jb + wc + (n<<4) + (lane&15);
    float bb = bias[jl];
    int hh = jl>>6, hd = jl&63;
    #pragma unroll
    for (int m=0;m<4;++m){
      int r0 = rbase + wr + (m<<4) + ((lane>>4)<<2);
      size_t base = ((size_t)(r0>>6)<<15) + ((size_t)hh<<12);
      if (mat==2){                     // Vt[b][h][hd][s]: 4 consecutive s -> 8B store
        u16x4 pk;
        pk.x=f2bf(acc[m][n][0]+bb); pk.y=f2bf(acc[m][n][1]+bb);
        pk.z=f2bf(acc[m][n][2]+bb); pk.w=f2bf(acc[m][n][3]+bb);
        *(u16x4*)(Out + base + (hd<<6) + (r0&63)) = pk;
      } else {                         // Q/K[b][h][s][hd]
        #pragma unroll
        for (int reg=0;reg<4;++reg){
          int r = r0+reg;
          Out[base + ((size_t)(r&63)<<6) + hd] = f2bf(acc[m][n][reg]+bb);
        }
      }
    }
  }
}

// ---------------- K2: attention, 1 block = 1 batch, 1 wave = 1 head ----------------
__global__ __launch_bounds__(512) void attn_k(
    u16* __restrict__ QO, const u16* __restrict__ Kb, const u16* __restrict__ Vt,
    const int* __restrict__ ray, const int* __restrict__ att)
{
  __shared__ __align__(16) u8 msk[2][4096];
  __shared__ __align__(16) u16 Plds[8][4096];  // 8KB per wave, XOR-swizzled
  const int b = blockIdx.x;
  const int lane = threadIdx.x&63, h = threadIdx.x>>6;
  u16* Qb = QO + ((size_t)b<<15) + (h<<12);
  const u16* Kh = Kb + ((size_t)b<<15) + (h<<12);
  const u16* Vh = Vt + ((size_t)b<<15) + (h<<12);
  if (h>=6){                           // stage dynamic mask int32 -> u8 (wave-private)
    const uint4* mg = (const uint4*)((h==6?ray:att) + ((size_t)b<<12));
    #pragma unroll
    for (int j=0;j<16;++j){
      int g = (j<<6) + lane;           // uint4 index 0..1023 (4096 ints/batch)
      uint4 w = mg[g];
      uint32_t pk = (w.x!=0u ? 1u:0u) | (w.y!=0u ? 0x100u:0u)
                  | (w.z!=0u ? 0x10000u:0u) | (w.w!=0u ? 0x1000000u:0u);
      *(uint32_t*)&msk[h-6][g<<2] = pk;
    }
  }
  const int tl = lane&15, lg = lane>>4;
  bf16x8 qf[4][2], kf[4][2];
  #pragma unroll
  for (int m=0;m<4;++m)
    #pragma unroll
    for (int kk=0;kk<2;++kk){
      int off = (((m<<4)+tl)<<6) + (kk<<5) + (lg<<3);
      qf[m][kk] = *(const bf16x8*)(Qb + off);
      kf[m][kk] = *(const bf16x8*)(Kh + off);
    }
  f32x4 sc[4][4] = {};
  #pragma unroll
  for (int m=0;m<4;++m)
    #pragma unroll
    for (int n=0;n<4;++n){
      sc[m][n] = __builtin_amdgcn_mfma_f32_16x16x32_bf16(qf[m][0], kf[n][0], sc[m][n], 0,0,0);
      sc[m][n] = __builtin_amdgcn_mfma_f32_16x16x32_bf16(qf[m][1], kf[n][1], sc[m][n], 0,0,0);
    }
  // mask + row softmax (rows live in 16-lane groups) + P -> swizzled LDS
  char* pw = (char*)(Plds[h]);
  #pragma unroll
  for (int m=0;m<4;++m){
    #pragma unroll
    for (int reg=0;reg<4;++reg){
      int r = (m<<4) + (lg<<2) + reg;
      int ri = r>>3, fi = r&7;
      float v4[4]; float mx = -3e38f;
      #pragma unroll
      for (int n=0;n<4;++n){
        int t = (n<<4) + tl;
        int rj = t>>3, fj = t&7;
        int dr = ri>rj?ri-rj:rj-ri, df = fi>fj?fi-fj:fj-fi;
        bool keep;
        if      (h==0) keep = (fj==fi);
        else if (h==1) keep = (rj==ri);
        else if (h==2) keep = ((ri-fi)==(rj-fj));
        else if (h==3) keep = ((ri+fi)==(rj+fj));
        else if (h==4) keep = ((dr==2&&df==1)||(dr==1&&df==2)||(r==t));
        else if (h==5) keep = (dr<=1&&df<=1);
        else           keep = (r==t) || (msk[h-6][(r<<6)+t] != 0);
        float s = keep ? sc[m][n][reg]*0.125f : -1e9f;
        v4[n] = s; mx = fmaxf(mx, s);
      }
      mx = fmaxf(mx, __shfl_xor(mx,1)); mx = fmaxf(mx, __shfl_xor(mx,2));
      mx = fmaxf(mx, __shfl_xor(mx,4)); mx = fmaxf(mx, __shfl_xor(mx,8));
      float sum = 0.f;
      #pragma unroll
      for (int n=0;n<4;++n){ float e = __expf(v4[n]-mx); v4[n]=e; sum+=e; }
      sum += __shfl_xor(sum,1); sum += __shfl_xor(sum,2);
      sum += __shfl_xor(sum,4); sum += __shfl_xor(sum,8);
      float inv = 1.0f/sum;
      #pragma unroll
      for (int n=0;n<4;++n){
        int t = (n<<4) + tl;
        int off = ((r<<7) + (t<<1)) ^ ((r&7)<<4);
        *(u16*)(pw + off) = f2bf(v4[n]*inv);
      }
    }
  }
  // PV: A = P (LDS, swizzled), B = V via Vt rows (contiguous 16B)
  bf16x8 pf[4][2], vf[4][2];
  #pragma unroll
  for (int m=0;m<4;++m){
    int row = (m<<4) + tl;
    #pragma unroll
    for (int kk=0;kk<2;++kk){
      int koff = ((((kk<<2)+lg) ^ (row&7))<<4);
      pf[m][kk] = *(const bf16x8*)(pw + (row<<7) + koff);
    }
  }
  #pragma unroll
  for (int n=0;n<4;++n)
    #pragma unroll
    for (int kk=0;kk<2;++kk){
      int off = (((n<<4)+tl)<<6) + (kk<<5) + (lg<<3);
      vf[n][kk] = *(const bf16x8*)(Vh + off);
    }
  f32x4 oacc[4][4] = {};
  #pragma unroll
  for (int m=0;m<4;++m)
    #pragma unroll
    for (int n=0;n<4;++n){
      oacc[m][n] = __builtin_amdgcn_mfma_f32_16x16x32_bf16(pf[m][0], vf[n][0], oacc[m][n], 0,0,0);
      oacc[m][n] = __builtin_amdgcn_mfma_f32_16x16x32_bf16(pf[m][1], vf[n][1], oacc[m][n], 0,0,0);
    }
  // O overwrites Q chunk in-place: layout [b][h][s][hd]
  #pragma unroll
  for (int m=0;m<4;++m)
    #pragma unroll
    for (int n=0;n<4;++n){
      int d = (n<<4) + tl;
      #pragma unroll
      for (int reg=0;reg<4;++reg){
        int s = (m<<4) + (lg<<2) + reg;
        Qb[(s<<6) + d] = f2bf(oacc[m][n][reg]);
      }
    }
}

// ---------------- K3: output projection ----------------
// A = O in [b][h][s][hd] bf16 (the Q buffer), B = Wo bf16, Y fp32 [131072][512]
__global__ __launch_bounds__(256) void k3_out(
    const u16* __restrict__ O, const u16* __restrict__ W, const float* __restrict__ bo,
    float* __restrict__ Y)
{
  __shared__ __align__(16) u16 As[8192];
  __shared__ __align__(16) u16 Bs[8192];
  const int tid = threadIdx.x, lane = tid&63, wv = tid>>6;
  const int jbase = blockIdx.x<<7;     // grid.x = 4
  const int rbase = blockIdx.y<<7;
  const int wr = (wv>>1)<<6, wc = (wv&1)<<6;
  f32x4 acc[4][4] = {};
  for (int kt=0; kt<8; ++kt){
    #pragma unroll
    for (int i=0;i<4;++i){
      int chunk = (wv<<2) + i;
      int row = (chunk<<3) + (lane>>3);
      int inner = (lane&7)<<4;
      int kbyte = inner ^ ((row&7)<<4);
      int r = rbase + row;
      size_t srcA = ((size_t)(r>>6)<<15) + ((size_t)kt<<12) + ((size_t)(r&63)<<6) + (kbyte>>1);
      gload16(O + srcA, (char*)As + (chunk<<10));
      int srcB = ((jbase + row)<<10) + (kt<<7) + kbyte;
      gload16((const char*)W + srcB, (char*)Bs + (chunk<<10));
    }
    __syncthreads();
    bf16x8 af[4][2], bfr[4][2];
    #pragma unroll
    for (int m=0;m<4;++m){
      int row = wr + (m<<4) + (lane&15);
      #pragma unroll
      for (int kk=0;kk<2;++kk){
        int koff = ((((kk<<2)+(lane>>4)) ^ (row&7))<<4);
        af[m][kk] = *(const bf16x8*)((char*)As + (row<<7) + koff);
      }
    }
    #pragma unroll
    for (int n=0;n<4;++n){
      int row = wc + (n<<4) + (lane&15);
      #pragma unroll
      for (int kk=0;kk<2;++kk){
        int koff = ((((kk<<2)+(lane>>4)) ^ (row&7))<<4);
        bfr[n][kk] = *(const bf16x8*)((char*)Bs + (row<<7) + koff);
      }
    }
    #pragma unroll
    for (int m=0;m<4;++m)
      #pragma unroll
      for (int n=0;n<4;++n){
        acc[m][n] = __builtin_amdgcn_mfma_f32_16x16x32_bf16(af[m][0], bfr[n][0], acc[m][n], 0,0,0);
        acc[m][n] = __builtin_amdgcn_mfma_f32_16x16x32_bf16(af[m][1], bfr[n][1], acc[m][n], 0,0,0);
      }
    __syncthreads();
  }
  #pragma unroll
  for (int n=0;n<4;++n){
    int j = jbase + wc + (n<<4) + (lane&15);
    float bb = bo[j];
    #pragma unroll
    for (int m=0;m<4;++m){
      int r0 = rbase + wr + (m<<4) + ((lane>>4)<<2);
      #pragma unroll
      for (int reg=0;reg<4;++reg){
        Y[(size_t)(r0+reg)*Dn + j] = acc[m][n][reg] + bb;
      }
    }
  }
}

extern "C" void kernel_launch(void* const* d_in, const int* in_sizes, int n_in,
                              void* d_out, int out_size, void* d_ws, size_t ws_size,
                              hipStream_t stream) {
  const float* x   = (const float*)d_in[0];
  const int*   ray = (const int*)d_in[1];
  const int*   att = (const int*)d_in[2];
  const float* Wq  = (const float*)d_in[3];
  const float* bq  = (const float*)d_in[4];
  const float* Wk  = (const float*)d_in[5];
  const float* bk  = (const float*)d_in[6];
  const float* Wv  = (const float*)d_in[7];
  const float* bv  = (const float*)d_in[8];
  const float* Wo  = (const float*)d_in[9];
  const float* bo  = (const float*)d_in[10];

  char* ws = (char*)d_ws;
  u16* Wqkv = (u16*)ws;                              // 1536*512*2 = 1.5MB
  u16* Wob  = (u16*)(ws + 1572864);                  // 512KB
  u16* Q    = (u16*)(ws + 2097152);                  // 134MB  [b][h][s][hd]; O aliases
  u16* Kb   = (u16*)(ws + 2097152 + 134217728);      // 134MB
  u16* Vt   = (u16*)(ws + 2097152 + 268435456);      // 134MB  [b][h][hd][s]
  float* out = (float*)d_out;

  hipLaunchKernelGGL(wconv_k, dim3(1024), dim3(256), 0, stream, Wq, Wk, Wv, Wo, Wqkv, Wob);
  hipLaunchKernelGGL(k1_qkv, dim3(12,1024), dim3(256), 0, stream, x, Wqkv, bq, bk, bv, Q, Kb, Vt);
  hipLaunchKernelGGL(attn_k, dim3(2048), dim3(512), 0, stream, Q, Kb, Vt, ray, att);
  hipLaunchKernelGGL(k3_out, dim3(4,1024), dim3(256), 0, stream, Q, Wob, bo, out);
}

// Round 3
// 1182.092 us; speedup vs baseline: 1.0471x; 1.0471x over previous
//
#include <hip/hip_runtime.h>
#include <stdint.h>

typedef unsigned short u16;
typedef unsigned char u8;
typedef short bf16x8 __attribute__((ext_vector_type(8)));
typedef float f32x4 __attribute__((ext_vector_type(4)));
typedef u16 u16x4 __attribute__((ext_vector_type(4)));

#define Bn 2048
#define Sn 64
#define Dn 512
#define Hn 8
#define MTOT (Bn*Sn)

__device__ __forceinline__ u16 f2bf(float f){
  uint32_t u = __builtin_bit_cast(uint32_t, f);
  u += 0x7FFFu + ((u>>16)&1u);   // round-to-nearest-even
  return (u16)(u>>16);
}

__device__ __forceinline__ void gload16(const void* g, void* lds){
  __builtin_amdgcn_global_load_lds((const __attribute__((address_space(1))) void*)g,
                                   (__attribute__((address_space(3))) void*)lds, 16, 0, 0);
}

// ---------------- weight conversion fp32 -> bf16 ----------------
__global__ __launch_bounds__(256) void wconv_k(
    const float* __restrict__ Wq, const float* __restrict__ Wk,
    const float* __restrict__ Wv, const float* __restrict__ Wo,
    u16* __restrict__ Wqkv, u16* __restrict__ Wob)
{
  int t = blockIdx.x*256 + threadIdx.x;      // 0..262143, 4 floats each
  int mat = t>>16, i4 = t&65535;
  const float4* src = (mat==0)?(const float4*)Wq:(mat==1)?(const float4*)Wk:
                      (mat==2)?(const float4*)Wv:(const float4*)Wo;
  float4 v = src[i4];
  u16x4 o; o.x=f2bf(v.x); o.y=f2bf(v.y); o.z=f2bf(v.z); o.w=f2bf(v.w);
  if (mat<3) ((u16x4*)Wqkv)[t] = o;
  else       ((u16x4*)Wob)[i4] = o;
}

// ---------------- X conversion fp32 -> bf16 (one-shot, BW-bound) ----------------
__global__ __launch_bounds__(256) void xconv_k(
    const float* __restrict__ X, u16* __restrict__ Xb)
{
  int t = blockIdx.x*256 + threadIdx.x;      // 1,048,576 threads
  #pragma unroll
  for (int i=0;i<16;++i){
    int idx = t + i*1048576;                 // float4 index < 16,777,216
    float4 v = ((const float4*)X)[idx];
    u16x4 o; o.x=f2bf(v.x); o.y=f2bf(v.y); o.z=f2bf(v.z); o.w=f2bf(v.w);
    ((u16x4*)Xb)[idx] = o;
  }
}

// ---------------- K1: QKV projection GEMM ----------------
// A = Xb bf16, B = Wqkv bf16 (B^T layout); both via global_load_lds w/
// pre-swizzled source (rule #21). XCD-chunked bijective swizzle (m204):
// all 12 N-tiles of a row-block land on one XCD -> X rows served from L2.
// C: Q,K as [b][h][s][hd]; V transposed -> Vt [b][h][hd][s]
__global__ __launch_bounds__(256) void k1_qkv(
    const u16* __restrict__ Xb, const u16* __restrict__ W,
    const float* __restrict__ bq, const float* __restrict__ bk, const float* __restrict__ bv,
    u16* __restrict__ Q, u16* __restrict__ Kb, u16* __restrict__ Vt)
{
  __shared__ __align__(16) u16 As[8192];   // [128 rows][64 k] bf16, byte ^= (row&7)<<4
  __shared__ __align__(16) u16 Bs[8192];
  const int tid = threadIdx.x, lane = tid&63, wv = tid>>6;
  const int lin = blockIdx.x;              // 0..12287; XCD = lin%8 (HW round-robin)
  const int wgid = (lin&7)*1536 + (lin>>3);
  const int rb = wgid/12;
  const int nt = wgid - rb*12;             // N-tile fastest within XCD chunk
  const int jbase = nt<<7;
  const int rbase = rb<<7;
  const int wr = (wv>>1)<<6, wc = (wv&1)<<6;
  f32x4 acc[4][4] = {};

  for (int kt=0; kt<8; ++kt){
    #pragma unroll
    for (int i=0;i<4;++i){                 // A+B: 2x16KB via 1KB wave-issues
      int chunk = (wv<<2) + i;
      int row = (chunk<<3) + (lane>>3);
      int swz = ((lane&7)<<4) ^ ((row&7)<<4);
      gload16((const char*)Xb + (((size_t)(rbase+row))<<10) + (kt<<7) + swz,
              (char*)As + (chunk<<10));
      gload16((const char*)W  + (((size_t)(jbase+row))<<10) + (kt<<7) + swz,
              (char*)Bs + (chunk<<10));
    }
    __syncthreads();
    bf16x8 af[4][2], bfr[4][2];
    #pragma unroll
    for (int m=0;m<4;++m){
      int row = wr + (m<<4) + (lane&15);
      #pragma unroll
      for (int kk=0;kk<2;++kk){
        int koff = ((((kk<<2)+(lane>>4)) ^ (row&7))<<4);
        af[m][kk] = *(const bf16x8*)((char*)As + (row<<7) + koff);
      }
    }
    #pragma unroll
    for (int n=0;n<4;++n){
      int row = wc + (n<<4) + (lane&15);
      #pragma unroll
      for (int kk=0;kk<2;++kk){
        int koff = ((((kk<<2)+(lane>>4)) ^ (row&7))<<4);
        bfr[n][kk] = *(const bf16x8*)((char*)Bs + (row<<7) + koff);
      }
    }
    #pragma unroll
    for (int m=0;m<4;++m)
      #pragma unroll
      for (int n=0;n<4;++n){
        acc[m][n] = __builtin_amdgcn_mfma_f32_16x16x32_bf16(af[m][0], bfr[n][0], acc[m][n], 0,0,0);
        acc[m][n] = __builtin_amdgcn_mfma_f32_16x16x32_bf16(af[m][1], bfr[n][1], acc[m][n], 0,0,0);
      }
    __syncthreads();
  }
  // epilogue: bias + bf16 + scatter to head-blocked layouts
  const int mat = jbase>>9;            // 0=Q 1=K 2=V
  const float* bias = (mat==0)?bq:((mat==1)?bk:bv);
  u16* Out = (mat==0)?Q:((mat==1)?Kb:Vt);
  const int jb = jbase & 511;
  #pragma unroll
  for (int n=0;n<4;++n){
    int jl = jb + wc + (n<<4) + (lane&15);
    float bb = bias[jl];
    int hh = jl>>6, hd = jl&63;
    #pragma unroll
    for (int m=0;m<4;++m){
      int r0 = rbase + wr + (m<<4) + ((lane>>4)<<2);
      size_t base = ((size_t)(r0>>6)<<15) + ((size_t)hh<<12);
      if (mat==2){                     // Vt[b][h][hd][s]: 4 consecutive s -> 8B store
        u16x4 pk;
        pk.x=f2bf(acc[m][n][0]+bb); pk.y=f2bf(acc[m][n][1]+bb);
        pk.z=f2bf(acc[m][n][2]+bb); pk.w=f2bf(acc[m][n][3]+bb);
        *(u16x4*)(Out + base + (hd<<6) + (r0&63)) = pk;
      } else {                         // Q/K[b][h][s][hd]
        #pragma unroll
        for (int reg=0;reg<4;++reg){
          int r = r0+reg;
          Out[base + ((size_t)(r&63)<<6) + hd] = f2bf(acc[m][n][reg]+bb);
        }
      }
    }
  }
}

// ---------------- K2: attention, 1 block = 1 batch, 1 wave = 1 head ----------------
__global__ __launch_bounds__(512) void attn_k(
    u16* __restrict__ QO, const u16* __restrict__ Kb, const u16* __restrict__ Vt,
    const int* __restrict__ ray, const int* __restrict__ att)
{
  __shared__ __align__(16) u8 msk[2][4096];
  __shared__ __align__(16) u16 Plds[8][4096];  // 8KB per wave, XOR-swizzled
  const int b = blockIdx.x;
  const int lane = threadIdx.x&63, h = threadIdx.x>>6;
  u16* Qb = QO + ((size_t)b<<15) + (h<<12);
  const u16* Kh = Kb + ((size_t)b<<15) + (h<<12);
  const u16* Vh = Vt + ((size_t)b<<15) + (h<<12);
  if (h>=6){                           // stage dynamic mask int32 -> u8 (wave-private)
    const uint4* mg = (const uint4*)((h==6?ray:att) + ((size_t)b<<12));
    #pragma unroll
    for (int j=0;j<16;++j){
      int g = (j<<6) + lane;           // uint4 index 0..1023 (4096 ints/batch)
      uint4 w = mg[g];
      uint32_t pk = (w.x!=0u ? 1u:0u) | (w.y!=0u ? 0x100u:0u)
                  | (w.z!=0u ? 0x10000u:0u) | (w.w!=0u ? 0x1000000u:0u);
      *(uint32_t*)&msk[h-6][g<<2] = pk;
    }
  }
  const int tl = lane&15, lg = lane>>4;
  bf16x8 qf[4][2], kf[4][2];
  #pragma unroll
  for (int m=0;m<4;++m)
    #pragma unroll
    for (int kk=0;kk<2;++kk){
      int off = (((m<<4)+tl)<<6) + (kk<<5) + (lg<<3);
      qf[m][kk] = *(const bf16x8*)(Qb + off);
      kf[m][kk] = *(const bf16x8*)(Kh + off);
    }
  f32x4 sc[4][4] = {};
  #pragma unroll
  for (int m=0;m<4;++m)
    #pragma unroll
    for (int n=0;n<4;++n){
      sc[m][n] = __builtin_amdgcn_mfma_f32_16x16x32_bf16(qf[m][0], kf[n][0], sc[m][n], 0,0,0);
      sc[m][n] = __builtin_amdgcn_mfma_f32_16x16x32_bf16(qf[m][1], kf[n][1], sc[m][n], 0,0,0);
    }
  // mask + row softmax (rows live in 16-lane groups) + P -> swizzled LDS
  char* pw = (char*)(Plds[h]);
  #pragma unroll
  for (int m=0;m<4;++m){
    #pragma unroll
    for (int reg=0;reg<4;++reg){
      int r = (m<<4) + (lg<<2) + reg;
      int ri = r>>3, fi = r&7;
      float v4[4]; float mx = -3e38f;
      #pragma unroll
      for (int n=0;n<4;++n){
        int t = (n<<4) + tl;
        int rj = t>>3, fj = t&7;
        int dr = ri>rj?ri-rj:rj-ri, df = fi>fj?fi-fj:fj-fi;
        bool keep;
        if      (h==0) keep = (fj==fi);
        else if (h==1) keep = (rj==ri);
        else if (h==2) keep = ((ri-fi)==(rj-fj));
        else if (h==3) keep = ((ri+fi)==(rj+fj));
        else if (h==4) keep = ((dr==2&&df==1)||(dr==1&&df==2)||(r==t));
        else if (h==5) keep = (dr<=1&&df<=1);
        else           keep = (r==t) || (msk[h-6][(r<<6)+t] != 0);
        float s = keep ? sc[m][n][reg]*0.125f : -1e9f;
        v4[n] = s; mx = fmaxf(mx, s);
      }
      mx = fmaxf(mx, __shfl_xor(mx,1)); mx = fmaxf(mx, __shfl_xor(mx,2));
      mx = fmaxf(mx, __shfl_xor(mx,4)); mx = fmaxf(mx, __shfl_xor(mx,8));
      float sum = 0.f;
      #pragma unroll
      for (int n=0;n<4;++n){ float e = __expf(v4[n]-mx); v4[n]=e; sum+=e; }
      sum += __shfl_xor(sum,1); sum += __shfl_xor(sum,2);
      sum += __shfl_xor(sum,4); sum += __shfl_xor(sum,8);
      float inv = 1.0f/sum;
      #pragma unroll
      for (int n=0;n<4;++n){
        int t = (n<<4) + tl;
        int off = ((r<<7) + (t<<1)) ^ ((r&7)<<4);
        *(u16*)(pw + off) = f2bf(v4[n]*inv);
      }
    }
  }
  // PV: A = P (LDS, swizzled), B = V via Vt rows (contiguous 16B)
  bf16x8 pf[4][2], vf[4][2];
  #pragma unroll
  for (int m=0;m<4;++m){
    int row = (m<<4) + tl;
    #pragma unroll
    for (int kk=0;kk<2;++kk){
      int koff = ((((kk<<2)+lg) ^ (row&7))<<4);
      pf[m][kk] = *(const bf16x8*)(pw + (row<<7) + koff);
    }
  }
  #pragma unroll
  for (int n=0;n<4;++n)
    #pragma unroll
    for (int kk=0;kk<2;++kk){
      int off = (((n<<4)+tl)<<6) + (kk<<5) + (lg<<3);
      vf[n][kk] = *(const bf16x8*)(Vh + off);
    }
  f32x4 oacc[4][4] = {};
  #pragma unroll
  for (int m=0;m<4;++m)
    #pragma unroll
    for (int n=0;n<4;++n){
      oacc[m][n] = __builtin_amdgcn_mfma_f32_16x16x32_bf16(pf[m][0], vf[n][0], oacc[m][n], 0,0,0);
      oacc[m][n] = __builtin_amdgcn_mfma_f32_16x16x32_bf16(pf[m][1], vf[n][1], oacc[m][n], 0,0,0);
    }
  // O overwrites Q chunk in-place: layout [b][h][s][hd]
  #pragma unroll
  for (int m=0;m<4;++m)
    #pragma unroll
    for (int n=0;n<4;++n){
      int d = (n<<4) + tl;
      #pragma unroll
      for (int reg=0;reg<4;++reg){
        int s = (m<<4) + (lg<<2) + reg;
        Qb[(s<<6) + d] = f2bf(oacc[m][n][reg]);
      }
    }
}

// ---------------- K3: output projection ----------------
// A = O in [b][h][s][hd] bf16 (the Q buffer), B = Wo bf16, Y fp32 [131072][512]
// XCD-chunked swizzle: 4 N-tiles of a row-block colocate -> O rows from L2.
__global__ __launch_bounds__(256) void k3_out(
    const u16* __restrict__ O, const u16* __restrict__ W, const float* __restrict__ bo,
    float* __restrict__ Y)
{
  __shared__ __align__(16) u16 As[8192];
  __shared__ __align__(16) u16 Bs[8192];
  const int tid = threadIdx.x, lane = tid&63, wv = tid>>6;
  const int lin = blockIdx.x;              // 0..4095
  const int wgid = (lin&7)*512 + (lin>>3);
  const int nt = wgid&3, rb = wgid>>2;
  const int jbase = nt<<7;
  const int rbase = rb<<7;
  const int wr = (wv>>1)<<6, wc = (wv&1)<<6;
  f32x4 acc[4][4] = {};
  for (int kt=0; kt<8; ++kt){
    #pragma unroll
    for (int i=0;i<4;++i){
      int chunk = (wv<<2) + i;
      int row = (chunk<<3) + (lane>>3);
      int kbyte = ((lane&7)<<4) ^ ((row&7)<<4);
      int r = rbase + row;
      size_t srcA = ((size_t)(r>>6)<<15) + ((size_t)kt<<12) + ((size_t)(r&63)<<6) + (kbyte>>1);
      gload16(O + srcA, (char*)As + (chunk<<10));
      size_t srcB = (((size_t)(jbase + row))<<10) + (kt<<7) + kbyte;
      gload16((const char*)W + srcB, (char*)Bs + (chunk<<10));
    }
    __syncthreads();
    bf16x8 af[4][2], bfr[4][2];
    #pragma unroll
    for (int m=0;m<4;++m){
      int row = wr + (m<<4) + (lane&15);
      #pragma unroll
      for (int kk=0;kk<2;++kk){
        int koff = ((((kk<<2)+(lane>>4)) ^ (row&7))<<4);
        af[m][kk] = *(const bf16x8*)((char*)As + (row<<7) + koff);
      }
    }
    #pragma unroll
    for (int n=0;n<4;++n){
      int row = wc + (n<<4) + (lane&15);
      #pragma unroll
      for (int kk=0;kk<2;++kk){
        int koff = ((((kk<<2)+(lane>>4)) ^ (row&7))<<4);
        bfr[n][kk] = *(const bf16x8*)((char*)Bs + (row<<7) + koff);
      }
    }
    #pragma unroll
    for (int m=0;m<4;++m)
      #pragma unroll
      for (int n=0;n<4;++n){
        acc[m][n] = __builtin_amdgcn_mfma_f32_16x16x32_bf16(af[m][0], bfr[n][0], acc[m][n], 0,0,0);
        acc[m][n] = __builtin_amdgcn_mfma_f32_16x16x32_bf16(af[m][1], bfr[n][1], acc[m][n], 0,0,0);
      }
    __syncthreads();
  }
  #pragma unroll
  for (int n=0;n<4;++n){
    int j = jbase + wc + (n<<4) + (lane&15);
    float bb = bo[j];
    #pragma unroll
    for (int m=0;m<4;++m){
      int r0 = rbase + wr + (m<<4) + ((lane>>4)<<2);
      #pragma unroll
      for (int reg=0;reg<4;++reg){
        Y[(size_t)(r0+reg)*Dn + j] = acc[m][n][reg] + bb;
      }
    }
  }
}

extern "C" void kernel_launch(void* const* d_in, const int* in_sizes, int n_in,
                              void* d_out, int out_size, void* d_ws, size_t ws_size,
                              hipStream_t stream) {
  const float* x   = (const float*)d_in[0];
  const int*   ray = (const int*)d_in[1];
  const int*   att = (const int*)d_in[2];
  const float* Wq  = (const float*)d_in[3];
  const float* bq  = (const float*)d_in[4];
  const float* Wk  = (const float*)d_in[5];
  const float* bk  = (const float*)d_in[6];
  const float* Wv  = (const float*)d_in[7];
  const float* bv  = (const float*)d_in[8];
  const float* Wo  = (const float*)d_in[9];
  const float* bo  = (const float*)d_in[10];

  char* ws = (char*)d_ws;
  u16* Wqkv = (u16*)ws;                              // 1536*512*2 = 1.5MB
  u16* Wob  = (u16*)(ws + 1572864);                  // 512KB
  u16* Q    = (u16*)(ws + 2097152);                  // 134MB  [b][h][s][hd]; O aliases
  u16* Kb   = (u16*)(ws + 2097152 + 134217728);      // 134MB
  u16* Vt   = (u16*)(ws + 2097152 + 268435456);      // 134MB  [b][h][hd][s]
  u16* Xb   = (u16*)d_out;                           // 134MB bf16 X aliases d_out
                                                     // (consumed by k1 before k3 writes)
  float* out = (float*)d_out;

  hipLaunchKernelGGL(wconv_k, dim3(1024), dim3(256), 0, stream, Wq, Wk, Wv, Wo, Wqkv, Wob);
  hipLaunchKernelGGL(xconv_k, dim3(4096), dim3(256), 0, stream, x, Xb);
  hipLaunchKernelGGL(k1_qkv, dim3(12288), dim3(256), 0, stream, Xb, Wqkv, bq, bk, bv, Q, Kb, Vt);
  hipLaunchKernelGGL(attn_k, dim3(2048), dim3(512), 0, stream, Q, Kb, Vt, ray, att);
  hipLaunchKernelGGL(k3_out, dim3(4096), dim3(256), 0, stream, Q, Wob, bo, out);
}